// Round 2
// baseline (337.205 us; speedup 1.0000x reference)
//
#include <hip/hip_runtime.h>
#include <hip/hip_bf16.h>

typedef __bf16 bf16x8 __attribute__((ext_vector_type(8)));
typedef float floatx4 __attribute__((ext_vector_type(4)));
using bf16 = __hip_bfloat16;

#define S_    2048
#define NHEAD 16

// ---------------------------------------------------------------------------
// Cast fp32 -> bf16, 4 elems/thread.
// ---------------------------------------------------------------------------
__global__ void cast_f32_bf16_kernel(const float* __restrict__ src, bf16* __restrict__ dst) {
  int i = (blockIdx.x * 256 + threadIdx.x) * 4;
  float4 v = *(const float4*)(src + i);
  bf16 o[4] = {__float2bfloat16(v.x), __float2bfloat16(v.y),
               __float2bfloat16(v.z), __float2bfloat16(v.w)};
  *(uint2*)(dst + i) = *(const uint2*)o;
}

// ---------------------------------------------------------------------------
// Transpose+cast weights: src fp32 [K=1024][N=1024] -> dst bf16 [N][K].
// z=0..2: Wq/Wk/Wv -> wt_qkv rows [z*1024 ..]; z=3: Wo -> wt_o.
// ---------------------------------------------------------------------------
__global__ void transpose_w_kernel(const float* __restrict__ wq, const float* __restrict__ wk,
                                   const float* __restrict__ wv, const float* __restrict__ wo,
                                   bf16* __restrict__ wt_qkv, bf16* __restrict__ wt_o) {
  __shared__ bf16 tile[32][33];
  int mat = blockIdx.z;
  const float* src = (mat == 0) ? wq : (mat == 1) ? wk : (mat == 2) ? wv : wo;
  bf16* dst = (mat == 3) ? wt_o : wt_qkv + mat * 1024 * 1024;
  int tx = threadIdx.x, ty = threadIdx.y;
  int n0 = blockIdx.x * 32, k0 = blockIdx.y * 32;
#pragma unroll
  for (int j = 0; j < 32; j += 8)
    tile[ty + j][tx] = __float2bfloat16(src[(k0 + ty + j) * 1024 + n0 + tx]);
  __syncthreads();
#pragma unroll
  for (int j = 0; j < 32; j += 8)
    dst[(n0 + ty + j) * 1024 + k0 + tx] = tile[tx][ty + j];
}

// ---------------------------------------------------------------------------
// T5 relative-position bias LUT: tab[h*4096 + (delta+2048)] = bias(h, delta)
// Exact-integer bucket math (25-__clz(rpa^2) == floor(2*log2(rpa/8))).
// ---------------------------------------------------------------------------
__global__ void bias_table_kernel(const float* __restrict__ rel_bias, float* __restrict__ tab) {
  int idx = blockIdx.x * 256 + threadIdx.x;   // 16*4096 = 65536
  int h = idx >> 12, j = idx & 4095;
  int delta = j - 2048;                        // k - q
  int rb = (delta > 0) ? 16 : 0;
  int rpa = delta < 0 ? -delta : delta;
  int bsmall;
  if (rpa < 8) {
    bsmall = rpa;
  } else {
    int lg = 25 - __clz(rpa * rpa);            // floor(2*log2(rpa/8))
    bsmall = 8 + lg;
    if (bsmall > 15) bsmall = 15;
  }
  int bucket = rb + bsmall;
  tab[idx] = rel_bias[bucket * 16 + h];
}

// ---------------------------------------------------------------------------
// V transpose: qkv[(b*S+s)*3072 + 2048 + h*64 + d] -> vt[((b*16+h)*64+d)*S + s]
// ---------------------------------------------------------------------------
__global__ void transpose_v_kernel(const bf16* __restrict__ qkv, bf16* __restrict__ vt) {
  __shared__ bf16 tile[32][33];
  int bh = blockIdx.z;                         // b*16+h
  int b = bh >> 4, h = bh & 15;
  int s0 = blockIdx.x * 32, d0 = blockIdx.y * 32;
  int tx = threadIdx.x, ty = threadIdx.y;
#pragma unroll
  for (int j = 0; j < 32; j += 8)
    tile[ty + j][tx] = qkv[(long)(b * S_ + s0 + ty + j) * 3072 + 2048 + h * 64 + d0 + tx];
  __syncthreads();
#pragma unroll
  for (int j = 0; j < 32; j += 8)
    vt[((long)bh * 64 + d0 + ty + j) * S_ + s0 + tx] = tile[tx][ty + j];
}

// ---------------------------------------------------------------------------
// GEMM: C[M][N] = A[M][K] * Bt[N][K]^T, bf16 in / fp32 acc / TOUT out.
// 128x128 tile, BK=32, 256 threads (4 waves, each 64x64 = 4x4 MFMA tiles).
// ---------------------------------------------------------------------------
__device__ inline void store_out(bf16* p, float v) { *p = __float2bfloat16(v); }
__device__ inline void store_out(float* p, float v) { *p = v; }

template <typename TOUT>
__global__ __launch_bounds__(256) void gemm_bt_kernel(const bf16* __restrict__ A,
                                                      const bf16* __restrict__ Bt,
                                                      TOUT* __restrict__ C,
                                                      int M, int N, int K) {
  __shared__ bf16 As[128 * 32];
  __shared__ bf16 Bs[128 * 32];
  int t = threadIdx.x;
  int m0 = blockIdx.y * 128, n0 = blockIdx.x * 128;
  int w = t >> 6, lane = t & 63, ln = lane & 15, quad = lane >> 4;
  int wr = w >> 1, wc = w & 1;
  floatx4 acc[4][4];
  floatx4 zero = {0.f, 0.f, 0.f, 0.f};
#pragma unroll
  for (int i = 0; i < 4; i++)
#pragma unroll
    for (int j = 0; j < 4; j++) acc[i][j] = zero;

  int r = t >> 2, c = (t & 3) * 8;             // staging: rows 0..63 (+64 on 2nd)
  const bf16* Ag = A + (long)(m0 + r) * K + c;
  const bf16* Bg = Bt + (long)(n0 + r) * K + c;

  for (int k0 = 0; k0 < K; k0 += 32) {
    bf16x8 av0 = *(const bf16x8*)(Ag + k0);
    bf16x8 av1 = *(const bf16x8*)(Ag + (long)64 * K + k0);
    bf16x8 bv0 = *(const bf16x8*)(Bg + k0);
    bf16x8 bv1 = *(const bf16x8*)(Bg + (long)64 * K + k0);
    *(bf16x8*)&As[r * 32 + c] = av0;
    *(bf16x8*)&As[(r + 64) * 32 + c] = av1;
    *(bf16x8*)&Bs[r * 32 + c] = bv0;
    *(bf16x8*)&Bs[(r + 64) * 32 + c] = bv1;
    __syncthreads();
    bf16x8 af[4], bfv[4];
#pragma unroll
    for (int i = 0; i < 4; i++)
      af[i] = *(const bf16x8*)&As[(wr * 64 + i * 16 + ln) * 32 + quad * 8];
#pragma unroll
    for (int j = 0; j < 4; j++)
      bfv[j] = *(const bf16x8*)&Bs[(wc * 64 + j * 16 + ln) * 32 + quad * 8];
#pragma unroll
    for (int i = 0; i < 4; i++)
#pragma unroll
      for (int j = 0; j < 4; j++)
        acc[i][j] = __builtin_amdgcn_mfma_f32_16x16x32_bf16(af[i], bfv[j], acc[i][j], 0, 0, 0);
    __syncthreads();
  }

#pragma unroll
  for (int i = 0; i < 4; i++)
#pragma unroll
    for (int j = 0; j < 4; j++)
#pragma unroll
      for (int rr = 0; rr < 4; rr++)
        store_out(&C[(long)(m0 + wr * 64 + i * 16 + quad * 4 + rr) * N + n0 + wc * 64 + j * 16 + ln],
                  acc[i][j][rr]);
}

// ---------------------------------------------------------------------------
// Flash attention with T5 bias. Grid (S/64, B*H), 256 threads = 4 waves.
// Each wave: 16 q-rows. K-tiles of 32. Online softmax; P via LDS transform.
// ---------------------------------------------------------------------------
__global__ __launch_bounds__(256) void attn_kernel(const bf16* __restrict__ qkv,
                                                   const bf16* __restrict__ vt,
                                                   const float* __restrict__ bias_tab,
                                                   bf16* __restrict__ ctx) {
  __shared__ bf16 Vs[64 * 32];                 // V tile transposed: [d=64][k=32]
  __shared__ bf16 Ps[4][16 * 32];              // per-wave P tile [q=16][k=32]
  int t = threadIdx.x, w = t >> 6, lane = t & 63, ln = lane & 15, quad = lane >> 4;
  int bh = blockIdx.y, b = bh >> 4, h = bh & 15;
  int qb = blockIdx.x * 64 + w * 16;

  const bf16* qbase = qkv + (long)(b * S_) * 3072 + h * 64;
  const bf16* kbase = qkv + (long)(b * S_) * 3072 + 1024 + h * 64;
  const bf16* vbase = vt + (long)bh * 64 * S_;
  const float* btab = bias_tab + h * 4096;

  bf16x8 Qf0 = *(const bf16x8*)(qbase + (long)(qb + ln) * 3072 + quad * 8);
  bf16x8 Qf1 = *(const bf16x8*)(qbase + (long)(qb + ln) * 3072 + 32 + quad * 8);

  float m_run[4], l_run[4];
  floatx4 o[4];
  floatx4 zero = {0.f, 0.f, 0.f, 0.f};
#pragma unroll
  for (int rr = 0; rr < 4; rr++) { m_run[rr] = -1e30f; l_run[rr] = 0.f; }
#pragma unroll
  for (int j2 = 0; j2 < 4; j2++) o[j2] = zero;

  int vd = t >> 2, vc = (t & 3) * 8;           // V staging: d row, col chunk

  for (int k0 = 0; k0 < S_; k0 += 32) {
    bf16x8 vv = *(const bf16x8*)(vbase + (long)vd * S_ + k0 + vc);
    // K fragments (B-operand: lane holds K[k0+kt*16+ln][d=quad*8+j])
    bf16x8 k00 = *(const bf16x8*)(kbase + (long)(k0 + ln) * 3072 + quad * 8);
    bf16x8 k01 = *(const bf16x8*)(kbase + (long)(k0 + ln) * 3072 + 32 + quad * 8);
    bf16x8 k10 = *(const bf16x8*)(kbase + (long)(k0 + 16 + ln) * 3072 + quad * 8);
    bf16x8 k11 = *(const bf16x8*)(kbase + (long)(k0 + 16 + ln) * 3072 + 32 + quad * 8);

    __syncthreads();                            // prev iter's Vs/Ps reads done
    *(bf16x8*)&Vs[vd * 32 + vc] = vv;

    floatx4 sc0 = zero, sc1 = zero;
    sc0 = __builtin_amdgcn_mfma_f32_16x16x32_bf16(Qf0, k00, sc0, 0, 0, 0);
    sc0 = __builtin_amdgcn_mfma_f32_16x16x32_bf16(Qf1, k01, sc0, 0, 0, 0);
    sc1 = __builtin_amdgcn_mfma_f32_16x16x32_bf16(Qf0, k10, sc1, 0, 0, 0);
    sc1 = __builtin_amdgcn_mfma_f32_16x16x32_bf16(Qf1, k11, sc1, 0, 0, 0);

    float al[4];
#pragma unroll
    for (int rr = 0; rr < 4; rr++) {
      int q = qb + quad * 4 + rr;
      float s0 = sc0[rr] + btab[(k0 + ln) - q + 2048];
      float s1 = sc1[rr] + btab[(k0 + 16 + ln) - q + 2048];
      float mx = fmaxf(s0, s1);
#pragma unroll
      for (int off = 1; off < 16; off <<= 1) mx = fmaxf(mx, __shfl_xor(mx, off));
      float mn = fmaxf(m_run[rr], mx);
      float a = __expf(m_run[rr] - mn);
      m_run[rr] = mn;
      float p0 = __expf(s0 - mn);
      float p1 = __expf(s1 - mn);
      float srow = p0 + p1;
#pragma unroll
      for (int off = 1; off < 16; off <<= 1) srow += __shfl_xor(srow, off);
      l_run[rr] = l_run[rr] * a + srow;
      al[rr] = a;
      Ps[w][(quad * 4 + rr) * 32 + ln] = __float2bfloat16(p0);
      Ps[w][(quad * 4 + rr) * 32 + 16 + ln] = __float2bfloat16(p1);
    }
    floatx4 av; av[0] = al[0]; av[1] = al[1]; av[2] = al[2]; av[3] = al[3];
#pragma unroll
    for (int j2 = 0; j2 < 4; j2++) o[j2] *= av;

    __syncthreads();                            // Vs staged + Ps written
    bf16x8 Pf = *(const bf16x8*)&Ps[w][ln * 32 + quad * 8];
#pragma unroll
    for (int j2 = 0; j2 < 4; j2++) {
      bf16x8 bv = *(const bf16x8*)&Vs[(j2 * 16 + ln) * 32 + quad * 8];
      o[j2] = __builtin_amdgcn_mfma_f32_16x16x32_bf16(Pf, bv, o[j2], 0, 0, 0);
    }
  }

#pragma unroll
  for (int j2 = 0; j2 < 4; j2++)
#pragma unroll
    for (int rr = 0; rr < 4; rr++) {
      int q = qb + quad * 4 + rr;
      ctx[(long)(b * S_ + q) * 1024 + h * 64 + j2 * 16 + ln] =
          __float2bfloat16(o[j2][rr] / l_run[rr]);
    }
}

// ---------------------------------------------------------------------------
extern "C" void kernel_launch(void* const* d_in, const int* in_sizes, int n_in,
                              void* d_out, int out_size, void* d_ws, size_t ws_size,
                              hipStream_t stream) {
  (void)in_sizes; (void)n_in; (void)out_size; (void)ws_size;
  const float* hidden   = (const float*)d_in[0];   // [2,2048,1024] fp32
  const float* Wq       = (const float*)d_in[1];   // [1024,1024] fp32
  const float* Wk       = (const float*)d_in[2];
  const float* Wv       = (const float*)d_in[3];
  const float* Wo       = (const float*)d_in[4];
  const float* rel_bias = (const float*)d_in[5];   // [32,16] fp32

  char* ws = (char*)d_ws;
  bf16*  hbf    = (bf16*)(ws + 0);                 //  8 MB: [4096][1024] bf16
  bf16*  wt_qkv = (bf16*)(ws + 8388608);           //  6 MB: [3072][1024]
  bf16*  wt_o   = (bf16*)(ws + 14680064);          //  2 MB: [1024][1024]
  float* btab   = (float*)(ws + 16777216);         // 256 KB: [16][4096]
  bf16*  qkv    = (bf16*)(ws + 17039360);          // 24 MB: [4096][3072]
  bf16*  vt     = (bf16*)(ws + 42205184);          //  8 MB: [32][64][2048]
  bf16*  ctx    = (bf16*)(ws + 50593792);          //  8 MB: [4096][1024]

  cast_f32_bf16_kernel<<<dim3(4096), dim3(256), 0, stream>>>(hidden, hbf);
  transpose_w_kernel<<<dim3(32, 32, 4), dim3(32, 8), 0, stream>>>(Wq, Wk, Wv, Wo, wt_qkv, wt_o);
  bias_table_kernel<<<dim3(256), dim3(256), 0, stream>>>(rel_bias, btab);
  gemm_bt_kernel<bf16><<<dim3(24, 32), dim3(256), 0, stream>>>(hbf, wt_qkv, qkv, 4096, 3072, 1024);
  transpose_v_kernel<<<dim3(64, 2, 32), dim3(32, 8), 0, stream>>>(qkv, vt);
  attn_kernel<<<dim3(32, 32), dim3(256), 0, stream>>>(qkv, vt, btab, ctx);
  gemm_bt_kernel<float><<<dim3(8, 32), dim3(256), 0, stream>>>(ctx, wt_o, (float*)d_out, 4096, 1024, 1024);
}